// Round 7
// baseline (450.336 us; speedup 1.0000x reference)
//
#include <hip/hip_runtime.h>
#include <stdint.h>

// Problem: B,T,C = 2,768,64; N_HEAD=64 -> head_dim=1; fp32 buffers.
// R6 post-mortem: proj's xr[h] dynamic register-array index likely forced the
// x row into scratch (private global-backed) -> proj regression. attn models
// still unverified (no counters since R3: fills flood rocprof top-5).
// R7 = probe round: attn repeats its body 8x in-kernel (rep arg) so its
// dispatch exceeds the 40us fill cutoff and appears in rocprof WITH counters;
// (dur - ovh)/8 gives true attn time. proj fixed (no dynamic reg indexing).
constexpr int Tc = 768;
constexpr int Hc = 64;
constexpr int Bc = 2;
constexpr float LOG2E = 1.44269504088896f;
constexpr size_t SLAB = (size_t)Bc * Hc * Tc;   // 98304 floats per slab

typedef float v2f __attribute__((ext_vector_type(2)));
typedef float v4f __attribute__((ext_vector_type(4)));

// ---------------------------------------------------------------------------
// Kernel 1: projection into transposed slabs (contiguous in t per (b,h)):
//   qs[(b*64+h)*768+t] = LOG2E * dot(x[b,t,:], Wq[h,:])
//   ks[..]             = dot(x[b,t,:], Wk[h,:])
//   vs[..]             = x[b,t,h] * vtmp[h] * ptmp[h]
// grid (24 row-tiles, 16 h-groups) x 256; lane owns one row (constant-index
// register array only!), wave owns one head (W rows via s_load).
// ---------------------------------------------------------------------------
__global__ __launch_bounds__(256) void proj_kernel(
    const float* __restrict__ x, const float* __restrict__ W,
    const float* __restrict__ vtmp, const float* __restrict__ ptmp,
    float* __restrict__ qs, float* __restrict__ ks, float* __restrict__ vs)
{
    const int lane = threadIdx.x & 63;
    const int w    = __builtin_amdgcn_readfirstlane(threadIdx.x >> 6);
    const int g    = blockIdx.x * 64 + lane;     // global row in [0,1536)
    const int bh0  = (g / Tc) * Hc;              // b*64 (64 | 768: no straddle)
    const int t    = g % Tc;
    const int h    = blockIdx.y * 4 + w;         // wave-uniform head

    float xr[64];
    const v4f* xp = (const v4f*)(x + (size_t)g * 64);
#pragma unroll
    for (int c = 0; c < 16; ++c) ((v4f*)xr)[c] = xp[c];

    const float* __restrict__ wq = W + h * 64;
    const float* __restrict__ wk = W + (64 + h) * 64;
    float aq = 0.f, ak = 0.f;
#pragma unroll
    for (int c = 0; c < 64; ++c) {               // constant indices only
        aq = fmaf(xr[c], wq[c], aq);
        ak = fmaf(xr[c], wk[c], ak);
    }
    const size_t o = (size_t)(bh0 + h) * Tc + t;   // lane-coalesced
    qs[o] = aq * LOG2E;
    ks[o] = ak;
    // NOTE: global load, NOT xr[h] — dynamic index into a register array
    // forces the whole array to scratch (suspected R6 regression).
    vs[o] = x[(size_t)g * 64 + h] * vtmp[h] * ptmp[h];
}

// 16-lane-group sum via DPP row_shr (works within a row of 16 lanes).
// Group total lands in lane (group*16 + 15).
__device__ __forceinline__ float dpp16_reduce_add(float v) {
    v += __int_as_float(__builtin_amdgcn_update_dpp(0, __float_as_int(v), 0x111, 0xf, 0xf, true));
    v += __int_as_float(__builtin_amdgcn_update_dpp(0, __float_as_int(v), 0x112, 0xf, 0xf, true));
    v += __int_as_float(__builtin_amdgcn_update_dpp(0, __float_as_int(v), 0x114, 0xf, 0xf, true));
    v += __int_as_float(__builtin_amdgcn_update_dpp(0, __float_as_int(v), 0x118, 0xf, 0xf, true));
    return v;
}

// ---------------------------------------------------------------------------
// Kernel 2: attention v4. 16-lane groups: lane owns a CONTIGUOUS 48-j chunk
// (preloaded as 12+12 dwordx4 -> registers, zero in-loop memory); each wave
// processes 4 rows per pass (q per-lane, no s_load/readlane), 4 passes = 16
// rows. Packed v2f math (v_pk_fma/add), 4-step DPP reduce per 16-lane group.
// grid (12,64,2) x 256. rep: in-kernel body repeat for the timing probe
// (stores every iter; asm barrier defeats LICM).
// ---------------------------------------------------------------------------
__global__ __launch_bounds__(256, 4) void attn_kernel(
    const float* __restrict__ qs, const float* __restrict__ ks,
    const float* __restrict__ vs, float* __restrict__ out, int rep)
{
    const int lane = threadIdx.x & 63;
    const int w    = __builtin_amdgcn_readfirstlane(threadIdx.x >> 6);
    const int l16  = lane & 15;
    const int rg   = lane >> 4;           // row-group 0..3
    const int rt   = blockIdx.x;          // 0..11
    const int h    = blockIdx.y;
    const int b    = blockIdx.z;
    const int bh   = b * Hc + h;

    // slopes[h] = 2^(-(h+1)/8) (H=64), folded with log2(e)
    const float slope2 = exp2f(-0.125f * (float)(h + 1)) * LOG2E;

    const float* __restrict__ kp = ks + (size_t)bh * Tc;
    const float* __restrict__ vp = vs + (size_t)bh * Tc;
    const float* __restrict__ qp = qs + (size_t)bh * Tc;

    // ---- preload this lane's 48 k and 48 v (contiguous chunk) ----
    const int jb = l16 * 48;
    v2f k2[24], v2[24];
#pragma unroll
    for (int r = 0; r < 12; ++r) {
        ((v4f*)k2)[r] = *(const v4f*)(kp + jb + 4 * r);
        ((v4f*)v2)[r] = *(const v4f*)(vp + jb + 4 * r);
    }
    // ---- preload q for this lane's 4 rows (one per pass) ----
    const int i00 = rt * 64 + w * 16 + rg;
    float ql[4];
#pragma unroll
    for (int p = 0; p < 4; ++p) ql[p] = qp[i00 + 4 * p];

    const float jbf   = (float)jb;
    const v2f   step2 = {2.f * slope2, 2.f * slope2};

    for (int it = 0; it < rep; ++it) {
        float anchor = jbf;
        asm volatile("" : "+v"(anchor));  // block LICM from hoisting the body
#pragma unroll
        for (int p = 0; p < 4; ++p) {
            const int   i  = i00 + 4 * p;
            const float fi = (float)i;
            const float q  = ql[p];
            v2f dj2;
            dj2.x = (anchor - fi) * slope2;       // slope2*(jb - i)
            dj2.y = dj2.x + slope2;
            const v2f q2 = {q, q};
            v2f sum2 = {0.f, 0.f}, acc2 = {0.f, 0.f};
            // scores bounded (|q.k| small, bias <= 0): no max-subtraction
#pragma unroll
            for (int g2 = 0; g2 < 24; ++g2) {
                v2f bias = __builtin_elementwise_min(dj2, (v2f){0.f, 0.f});
                v2f sc   = q2 * k2[g2] + bias;    // v_pk_fma_f32
                v2f e;
                e.x = __builtin_amdgcn_exp2f(sc.x);
                e.y = __builtin_amdgcn_exp2f(sc.y);
                sum2 += e;                        // v_pk_add_f32
                acc2  = e * v2[g2] + acc2;        // v_pk_fma_f32
                dj2  += step2;                    // v_pk_add_f32
            }
            float s = sum2.x + sum2.y;
            float a = acc2.x + acc2.y;
            s = dpp16_reduce_add(s);
            a = dpp16_reduce_add(a);
            if (l16 == 15) {
                out[((size_t)(b * Tc + i)) * 64 + h] =
                    a * __builtin_amdgcn_rcpf(s);
            }
        }
    }
}

extern "C" void kernel_launch(void* const* d_in, const int* in_sizes, int n_in,
                              void* d_out, int out_size, void* d_ws, size_t ws_size,
                              hipStream_t stream) {
    const float* x    = (const float*)d_in[0];
    const float* W    = (const float*)d_in[1];
    const float* vtmp = (const float*)d_in[2];
    const float* ptmp = (const float*)d_in[3];
    float* out = (float*)d_out;

    float* qsl = (float*)d_ws;
    float* ksl = qsl + SLAB;
    float* vsl = ksl + SLAB;

    proj_kernel<<<dim3(24, 16), 256, 0, stream>>>(x, W, vtmp, ptmp, qsl, ksl, vsl);
    // rep=8 probe: lifts attn above the 40us fill cutoff -> rocprof top-5
    // with counters; true attn time = (measured - preload)/8.
    attn_kernel<<<dim3(12, Hc, Bc), 256, 0, stream>>>(qsl, ksl, vsl, out, 8);
}

// Round 8
// 80.921 us; speedup vs baseline: 5.5651x; 5.5651x over previous
//
#include <hip/hip_runtime.h>
#include <stdint.h>

// Problem: B,T,C = 2,768,64; N_HEAD=64 -> head_dim=1; fp32 buffers.
// Calibration (R7 probe): harness overhead ~52 us (268MB ws poison fill);
// proj_kernel ~3 us; R7's 48-j/lane register-cache attn SPILLED to scratch
// (FETCH 864MB, HBM-bound, 49 us/rep) -> dead end. R3-verified shape
// (kr[12]/vr[12], VGPR=36, no spill) is the attn skeleton.
// Model update: v_exp_f32 ~ 16-20 cyc/wave64 (1/8 rate) -> attn floor ~9-14 us.
constexpr int Tc = 768;
constexpr int Hc = 64;
constexpr int Bc = 2;
constexpr float LOG2E = 1.44269504088896f;
constexpr size_t SLAB = (size_t)Bc * Hc * Tc;   // 98304 floats per slab

typedef float v4f __attribute__((ext_vector_type(4)));

// ---------------------------------------------------------------------------
// Kernel 1: projection into transposed slabs (contiguous in t per (b,h)):
//   qs[(b*64+h)*768+t] = LOG2E * dot(x[b,t,:], Wq[h,:])
//   ks[..]             = dot(x[b,t,:], Wk[h,:])
//   vs[..]             = x[b,t,h] * vtmp[h] * ptmp[h]
// grid (24,16) x 256; lane owns one row (constant register indices only —
// dynamic index forces scratch, R6 lesson), wave owns one head (s_load W).
// Measured ~3 us (R7).
// ---------------------------------------------------------------------------
__global__ __launch_bounds__(256) void proj_kernel(
    const float* __restrict__ x, const float* __restrict__ W,
    const float* __restrict__ vtmp, const float* __restrict__ ptmp,
    float* __restrict__ qs, float* __restrict__ ks, float* __restrict__ vs)
{
    const int lane = threadIdx.x & 63;
    const int w    = __builtin_amdgcn_readfirstlane(threadIdx.x >> 6);
    const int g    = blockIdx.x * 64 + lane;     // global row in [0,1536)
    const int bh0  = (g / Tc) * Hc;              // b*64 (64 | 768: no straddle)
    const int t    = g % Tc;
    const int h    = blockIdx.y * 4 + w;         // wave-uniform head

    float xr[64];
    const v4f* xp = (const v4f*)(x + (size_t)g * 64);
#pragma unroll
    for (int c = 0; c < 16; ++c) ((v4f*)xr)[c] = xp[c];

    const float* __restrict__ wq = W + h * 64;
    const float* __restrict__ wk = W + (64 + h) * 64;
    float aq = 0.f, ak = 0.f;
#pragma unroll
    for (int c = 0; c < 64; ++c) {               // constant indices only
        aq = fmaf(xr[c], wq[c], aq);
        ak = fmaf(xr[c], wk[c], ak);
    }
    const size_t o = (size_t)(bh0 + h) * Tc + t;   // lane-coalesced
    qs[o] = aq * LOG2E;
    ks[o] = ak;
    vs[o] = x[(size_t)g * 64 + h] * vtmp[h] * ptmp[h];   // global reload, not xr[h]
}

// 64-lane sum via DPP (VALU pipe, no LDS). Total lands in lane 63.
__device__ __forceinline__ float dpp_reduce_add(float v) {
    v += __int_as_float(__builtin_amdgcn_update_dpp(0, __float_as_int(v), 0x111, 0xf, 0xf, true));
    v += __int_as_float(__builtin_amdgcn_update_dpp(0, __float_as_int(v), 0x112, 0xf, 0xf, true));
    v += __int_as_float(__builtin_amdgcn_update_dpp(0, __float_as_int(v), 0x114, 0xf, 0xf, true));
    v += __int_as_float(__builtin_amdgcn_update_dpp(0, __float_as_int(v), 0x118, 0xf, 0xf, true));
    v += __int_as_float(__builtin_amdgcn_update_dpp(0, __float_as_int(v), 0x142, 0xf, 0xf, true));
    v += __int_as_float(__builtin_amdgcn_update_dpp(0, __float_as_int(v), 0x143, 0xf, 0xf, true));
    return v;
}

// ---------------------------------------------------------------------------
// Kernel 2: attention, lane-per-j (R3-proven no-spill shape: 36-reg cache).
// Lane caches k,v for its 12 strided j's (coalesced one-time loads); per row:
// q via uniform s_load, 12x {sub,min,fmac,exp2,add,fmac}, DPP64 reduce,
// lane63 store. Zero LDS, zero in-loop VMEM, zero spill (VGPR ~60).
// grid (12,64,2) = 1536 blocks = 6/CU exact; 4 waves x 16 rows each.
// ---------------------------------------------------------------------------
__global__ __launch_bounds__(256, 6) void attn_kernel(
    const float* __restrict__ qs, const float* __restrict__ ks,
    const float* __restrict__ vs, float* __restrict__ out)
{
    const int lane = threadIdx.x & 63;
    const int w    = __builtin_amdgcn_readfirstlane(threadIdx.x >> 6);
    const int rt   = blockIdx.x;   // 0..11
    const int h    = blockIdx.y;
    const int b    = blockIdx.z;
    const int bh   = b * Hc + h;

    // slopes[h] = 2^(-(h+1)/8) (H=64), folded with log2(e)
    const float slope2 = exp2f(-0.125f * (float)(h + 1)) * LOG2E;

    const float* __restrict__ kp = ks + (size_t)bh * Tc;
    const float* __restrict__ vp = vs + (size_t)bh * Tc;
    const float* __restrict__ qp = qs + (size_t)bh * Tc;

    float kr[12], vr[12], bj[12];
#pragma unroll
    for (int r = 0; r < 12; ++r) {
        const int j = lane + 64 * r;      // coalesced
        kr[r] = kp[j];
        vr[r] = vp[j];
        bj[r] = slope2 * (float)j;
    }

    const int i0 = rt * 64 + w * 16;      // this wave's 16 rows
    float si = slope2 * (float)i0;
#pragma unroll 2
    for (int ii = 0; ii < 16; ++ii) {
        const int i  = i0 + ii;
        const float q = qp[i];            // uniform address -> s_load
        float sum = 0.f, acc = 0.f;
        // scores bounded (|q.k| small, bias <= 0): no max-subtraction needed
#pragma unroll
        for (int r = 0; r < 12; ++r) {
            float d = fminf(bj[r] - si, 0.f);            // slope*min(j-i,0)
            float e = __builtin_amdgcn_exp2f(fmaf(q, kr[r], d));
            sum += e;
            acc  = fmaf(e, vr[r], acc);
        }
        sum = dpp_reduce_add(sum);
        acc = dpp_reduce_add(acc);
        if (lane == 63) {
            out[((size_t)(b * Tc + i)) * 64 + h] = acc * __builtin_amdgcn_rcpf(sum);
        }
        si += slope2;
    }
}

extern "C" void kernel_launch(void* const* d_in, const int* in_sizes, int n_in,
                              void* d_out, int out_size, void* d_ws, size_t ws_size,
                              hipStream_t stream) {
    const float* x    = (const float*)d_in[0];
    const float* W    = (const float*)d_in[1];
    const float* vtmp = (const float*)d_in[2];
    const float* ptmp = (const float*)d_in[3];
    float* out = (float*)d_out;

    float* qsl = (float*)d_ws;
    float* ksl = qsl + SLAB;
    float* vsl = ksl + SLAB;

    proj_kernel<<<dim3(24, 16), 256, 0, stream>>>(x, W, vtmp, ptmp, qsl, ksl, vsl);
    attn_kernel<<<dim3(12, Hc, Bc), 256, 0, stream>>>(qsl, ksl, vsl, out);
}

// Round 9
// 78.193 us; speedup vs baseline: 5.7593x; 1.0349x over previous
//
#include <hip/hip_runtime.h>
#include <stdint.h>

// Problem: B,T,C = 2,768,64; N_HEAD=64 -> head_dim=1; fp32 buffers.
// Calibrated: harness overhead ~52 us; proj ~3 us (R7); attn R8 (lane-per-j,
// DPP64 reduce + per-row s_load q) ~26 us; R4 (uniform vector loads) ~27 us.
// R9 theory: the shared per-row overheads (16 serial s_loads + 12-op DPP
// chains per row ~= exp instr count) and/or slow trans pipe are the wall.
// -> lane-per-row: q, sum, acc per-lane; NO reductions, NO per-row s_loads;
// k/v broadcast from LDS via uniform-address ds_read_b64 (imm offsets).
constexpr int Tc = 768;
constexpr int Hc = 64;
constexpr int Bc = 2;
constexpr float LOG2E = 1.44269504088896f;
constexpr size_t SLAB = (size_t)Bc * Hc * Tc;   // 98304 floats per slab

typedef float v2f __attribute__((ext_vector_type(2)));
typedef float v4f __attribute__((ext_vector_type(4)));

// ---------------------------------------------------------------------------
// Kernel 1: projection into transposed slabs (contiguous in t per (b,h)):
//   qs[(b*64+h)*768+t] = LOG2E * dot(x[b,t,:], Wq[h,:])
//   ks[..]             = dot(x[b,t,:], Wk[h,:])
//   vs[..]             = x[b,t,h] * vtmp[h] * ptmp[h]
// grid (24,16) x 256; lane owns one row (constant register indices only —
// dynamic index forces scratch, R6 lesson), wave owns one head (s_load W).
// Measured ~3 us (R7).
// ---------------------------------------------------------------------------
__global__ __launch_bounds__(256) void proj_kernel(
    const float* __restrict__ x, const float* __restrict__ W,
    const float* __restrict__ vtmp, const float* __restrict__ ptmp,
    float* __restrict__ qs, float* __restrict__ ks, float* __restrict__ vs)
{
    const int lane = threadIdx.x & 63;
    const int w    = __builtin_amdgcn_readfirstlane(threadIdx.x >> 6);
    const int g    = blockIdx.x * 64 + lane;     // global row in [0,1536)
    const int bh0  = (g / Tc) * Hc;              // b*64 (64 | 768: no straddle)
    const int t    = g % Tc;
    const int h    = blockIdx.y * 4 + w;         // wave-uniform head

    float xr[64];
    const v4f* xp = (const v4f*)(x + (size_t)g * 64);
#pragma unroll
    for (int c = 0; c < 16; ++c) ((v4f*)xr)[c] = xp[c];

    const float* __restrict__ wq = W + h * 64;
    const float* __restrict__ wk = W + (64 + h) * 64;
    float aq = 0.f, ak = 0.f;
#pragma unroll
    for (int c = 0; c < 64; ++c) {               // constant indices only
        aq = fmaf(xr[c], wq[c], aq);
        ak = fmaf(xr[c], wk[c], ak);
    }
    const size_t o = (size_t)(bh0 + h) * Tc + t;   // lane-coalesced
    qs[o] = aq * LOG2E;
    ks[o] = ak;
    vs[o] = x[(size_t)g * 64 + h] * vtmp[h] * ptmp[h];   // global reload, not xr[h]
}

// ---------------------------------------------------------------------------
// Kernel 2: attention, lane-per-row. Block = (row-tile rt, h, b): 64 rows,
// lane = row. Stage kv interleaved {k[t],v[t]} into LDS once (coalesced from
// ws). Each of 4 waves covers a 192-j quarter: inner loop per j = one
// broadcast ds_read_b64 (uniform addr, imm offset) + {add,min,fma,exp2,add,
// fma}. Per-lane sum/acc -> NO cross-lane reduce, NO per-row s_load. 4
// partials combined via LDS. grid (12,64,2) = 6 blocks/CU, 24 waves/CU.
// ---------------------------------------------------------------------------
__global__ __launch_bounds__(256, 6) void attn_kernel(
    const float* __restrict__ qs, const float* __restrict__ ks,
    const float* __restrict__ vs, float* __restrict__ out)
{
    const int tid  = threadIdx.x;
    const int lane = tid & 63;
    const int w    = __builtin_amdgcn_readfirstlane(tid >> 6);
    const int rt   = blockIdx.x;   // 0..11
    const int h    = blockIdx.y;
    const int b    = blockIdx.z;
    const int bh   = b * Hc + h;

    __shared__ v2f  kv[Tc];              // interleaved {k[t], v[t]}
    __shared__ float psum[4][64], pacc[4][64];

    const float* __restrict__ kp = ks + (size_t)bh * Tc;
    const float* __restrict__ vp = vs + (size_t)bh * Tc;

    // ---- stage k,v into LDS (coalesced global reads, 3 t per thread) ----
#pragma unroll
    for (int r = 0; r < 3; ++r) {
        const int t = tid + 256 * r;
        v2f e; e.x = kp[t]; e.y = vp[t];
        kv[t] = e;                       // ds_write_b64
    }

    // ---- per-lane row state ----
    const int i = rt * 64 + lane;        // this lane's query row
    const float q = qs[(size_t)bh * Tc + i];   // coalesced, once
    // slopes[h] = 2^(-(h+1)/8) (H=64), folded with log2(e)
    const float slope2 = exp2f(-0.125f * (float)(h + 1)) * LOG2E;

    float cu[16];
#pragma unroll
    for (int u = 0; u < 16; ++u) cu[u] = slope2 * (float)u;

    __syncthreads();

    // ---- inner: this wave's 192-j quarter, uniform j -> LDS broadcast ----
    const int j0 = w * (Tc / 4);
    const v2f* __restrict__ kvq = &kv[j0];   // one addr reg; imm offsets
    float sum = 0.f, acc = 0.f;
    for (int c = 0; c < 12; ++c) {           // 12 chunks x 16 j
        // exact per-chunk base: slope2*(j_chunk - i), no drift accumulation
        const float mb = slope2 * (float)(j0 + 16 * c - i);
#pragma unroll
        for (int u = 0; u < 16; ++u) {
            v2f kvj = kvq[16 * c + u];       // ds_read_b64 broadcast
            float d = fminf(mb + cu[u], 0.f);            // slope*min(j-i,0)
            float e = __builtin_amdgcn_exp2f(fmaf(q, kvj.x, d));
            sum += e;
            acc  = fmaf(e, kvj.y, acc);
        }
    }
    psum[w][lane] = sum;
    pacc[w][lane] = acc;
    __syncthreads();

    // ---- combine 4 quarters, write out ----
    if (tid < 64) {
        float s = psum[0][lane] + psum[1][lane] + psum[2][lane] + psum[3][lane];
        float a = pacc[0][lane] + pacc[1][lane] + pacc[2][lane] + pacc[3][lane];
        out[((size_t)(b * Tc + rt * 64 + lane)) * 64 + h] =
            a * __builtin_amdgcn_rcpf(s);
    }
}

extern "C" void kernel_launch(void* const* d_in, const int* in_sizes, int n_in,
                              void* d_out, int out_size, void* d_ws, size_t ws_size,
                              hipStream_t stream) {
    const float* x    = (const float*)d_in[0];
    const float* W    = (const float*)d_in[1];
    const float* vtmp = (const float*)d_in[2];
    const float* ptmp = (const float*)d_in[3];
    float* out = (float*)d_out;

    float* qsl = (float*)d_ws;
    float* ksl = qsl + SLAB;
    float* vsl = ksl + SLAB;

    proj_kernel<<<dim3(24, 16), 256, 0, stream>>>(x, W, vtmp, ptmp, qsl, ksl, vsl);
    attn_kernel<<<dim3(12, Hc, Bc), 256, 0, stream>>>(qsl, ksl, vsl, out);
}

// Round 10
// 77.115 us; speedup vs baseline: 5.8398x; 1.0140x over previous
//
#include <hip/hip_runtime.h>
#include <stdint.h>

// Problem: B,T,C = 2,768,64; N_HEAD=64 -> head_dim=1; fp32 buffers.
// Calibrated: harness overhead ~52 us; proj ~3 us; attn structures R4/R8/R9
// all land 23-27 us (implied VALUBusy ~25%) -> wall is per-(row,j) cost.
// R10: (a) 2 rows/lane packed v2f (v_pk_fma/add; kvj broadcast amortized x2,
// 2 indep exp chains), (b) wave-uniform ALiBi truncation skip (~17% of exps),
// (c) grid (6,64,2)=3 blocks/CU, 12 waves/CU.
constexpr int Tc = 768;
constexpr int Hc = 64;
constexpr int Bc = 2;
constexpr float LOG2E = 1.44269504088896f;
constexpr size_t SLAB = (size_t)Bc * Hc * Tc;   // 98304 floats per slab

typedef float v2f __attribute__((ext_vector_type(2)));
typedef float v4f __attribute__((ext_vector_type(4)));

// ---------------------------------------------------------------------------
// Kernel 1: projection into transposed slabs (measured ~3 us, R7):
//   qs[(b*64+h)*768+t] = LOG2E * dot(x[b,t,:], Wq[h,:])
//   ks[..]             = dot(x[b,t,:], Wk[h,:])
//   vs[..]             = x[b,t,h] * vtmp[h] * ptmp[h]
// ---------------------------------------------------------------------------
__global__ __launch_bounds__(256) void proj_kernel(
    const float* __restrict__ x, const float* __restrict__ W,
    const float* __restrict__ vtmp, const float* __restrict__ ptmp,
    float* __restrict__ qs, float* __restrict__ ks, float* __restrict__ vs)
{
    const int lane = threadIdx.x & 63;
    const int w    = __builtin_amdgcn_readfirstlane(threadIdx.x >> 6);
    const int g    = blockIdx.x * 64 + lane;     // global row in [0,1536)
    const int bh0  = (g / Tc) * Hc;              // b*64 (64 | 768: no straddle)
    const int t    = g % Tc;
    const int h    = blockIdx.y * 4 + w;         // wave-uniform head

    float xr[64];
    const v4f* xp = (const v4f*)(x + (size_t)g * 64);
#pragma unroll
    for (int c = 0; c < 16; ++c) ((v4f*)xr)[c] = xp[c];

    const float* __restrict__ wq = W + h * 64;
    const float* __restrict__ wk = W + (64 + h) * 64;
    float aq = 0.f, ak = 0.f;
#pragma unroll
    for (int c = 0; c < 64; ++c) {               // constant indices only
        aq = fmaf(xr[c], wq[c], aq);
        ak = fmaf(xr[c], wk[c], ak);
    }
    const size_t o = (size_t)(bh0 + h) * Tc + t;   // lane-coalesced
    qs[o] = aq * LOG2E;
    ks[o] = ak;
    vs[o] = x[(size_t)g * 64 + h] * vtmp[h] * ptmp[h];   // global reload, not xr[h]
}

// ---------------------------------------------------------------------------
// Kernel 2: attention. Block = (rt: 128 rows, h, b); 4 waves = 4 j-quarters
// (192 j). Lane owns ROW PAIR (i, i+64) packed in v2f lanes; per j: one
// broadcast ds_read_b64 + packed {pk_add, 2x min, pk_fma, 2x exp2, pk_add,
// pk_fma}. Wave-uniform ALiBi skip: chunks with slope2*(i_min - j) > 28 bits
// contribute < 2^-28 rel -> skipped (early heads are local: h=0 d~21).
// grid (6,64,2) = 768 blocks = 3/CU, 12 waves/CU. LDS 10 KB.
// ---------------------------------------------------------------------------
__global__ __launch_bounds__(256, 3) void attn_kernel(
    const float* __restrict__ qs, const float* __restrict__ ks,
    const float* __restrict__ vs, float* __restrict__ out)
{
    const int tid  = threadIdx.x;
    const int lane = tid & 63;
    const int w    = __builtin_amdgcn_readfirstlane(tid >> 6);
    const int rt   = blockIdx.x;   // 0..5 (128-row tile)
    const int h    = blockIdx.y;
    const int b    = blockIdx.z;
    const int bh   = b * Hc + h;

    __shared__ v2f  kv[Tc];                  // interleaved {k[t], v[t]}, 6 KB
    __shared__ float psum[4][128], pacc[4][128];   // 4 KB

    const float* __restrict__ kp = ks + (size_t)bh * Tc;
    const float* __restrict__ vp = vs + (size_t)bh * Tc;
    const float* __restrict__ qp = qs + (size_t)bh * Tc;

    // ---- stage k,v into LDS (coalesced, 3 t per thread) ----
#pragma unroll
    for (int r = 0; r < 3; ++r) {
        const int t = tid + 256 * r;
        v2f e; e.x = kp[t]; e.y = vp[t];
        kv[t] = e;
    }

    // ---- per-lane row-pair state ----
    const int i0 = rt * 128 + lane;          // row pair (i0, i0+64)
    v2f q2; q2.x = qp[i0]; q2.y = qp[i0 + 64];   // coalesced, log2e folded
    // slopes[h] = 2^(-(h+1)/8) (H=64), folded with log2(e)
    const float slope2 = exp2f(-0.125f * (float)(h + 1)) * LOG2E;

    v2f cu2[16];
#pragma unroll
    for (int u = 0; u < 16; ++u) { cu2[u].x = slope2 * (float)u; cu2[u].y = cu2[u].x; }

    __syncthreads();

    // ---- wave-uniform ALiBi truncation: skip chunks fully below i_min - d ----
    const int j0 = w * (Tc / 4);
    int c0 = 0;
    {
        const int jskip = rt * 128 - (int)(28.f / slope2);  // bias < 2^-28 beyond
        if (jskip > j0) {
            c0 = (jskip - j0) >> 4;
            if (c0 > 12) c0 = 12;
        }
    }

    const v2f* __restrict__ kvq = &kv[j0];
    v2f sum2 = {0.f, 0.f}, acc2 = {0.f, 0.f};
    for (int c = c0; c < 12; ++c) {          // 16 j per chunk
        v2f mb2;                              // slope2*(j_chunk - i) per row
        mb2.x = slope2 * (float)(j0 + 16 * c - i0);
        mb2.y = slope2 * (float)(j0 + 16 * c - (i0 + 64));
#pragma unroll
        for (int u = 0; u < 16; ++u) {
            v2f kvj = kvq[16 * c + u];        // broadcast ds_read_b64
            v2f t2  = mb2 + cu2[u];           // v_pk_add_f32
            v2f bias;
            bias.x = fminf(t2.x, 0.f);
            bias.y = fminf(t2.y, 0.f);
            v2f kk = {kvj.x, kvj.x};
            v2f sc = q2 * kk + bias;          // v_pk_fma_f32
            v2f e;
            e.x = __builtin_amdgcn_exp2f(sc.x);
            e.y = __builtin_amdgcn_exp2f(sc.y);
            sum2 += e;                        // v_pk_add_f32
            v2f vv = {kvj.y, kvj.y};
            acc2 = e * vv + acc2;             // v_pk_fma_f32
        }
    }
    psum[w][lane]      = sum2.x;
    psum[w][lane + 64] = sum2.y;
    pacc[w][lane]      = acc2.x;
    pacc[w][lane + 64] = acc2.y;
    __syncthreads();

    // ---- combine 4 j-quarters for 128 rows, write out ----
    if (tid < 128) {
        float s = psum[0][tid] + psum[1][tid] + psum[2][tid] + psum[3][tid];
        float a = pacc[0][tid] + pacc[1][tid] + pacc[2][tid] + pacc[3][tid];
        out[((size_t)(b * Tc + rt * 128 + tid)) * 64 + h] =
            a * __builtin_amdgcn_rcpf(s);
    }
}

extern "C" void kernel_launch(void* const* d_in, const int* in_sizes, int n_in,
                              void* d_out, int out_size, void* d_ws, size_t ws_size,
                              hipStream_t stream) {
    const float* x    = (const float*)d_in[0];
    const float* W    = (const float*)d_in[1];
    const float* vtmp = (const float*)d_in[2];
    const float* ptmp = (const float*)d_in[3];
    float* out = (float*)d_out;

    float* qsl = (float*)d_ws;
    float* ksl = qsl + SLAB;
    float* vsl = ksl + SLAB;

    proj_kernel<<<dim3(24, 16), 256, 0, stream>>>(x, W, vtmp, ptmp, qsl, ksl, vsl);
    attn_kernel<<<dim3(6, Hc, Bc), 256, 0, stream>>>(qsl, ksl, vsl, out);
}